// Round 2
// 398.344 us; speedup vs baseline: 1.0524x; 1.0524x over previous
//
#include <hip/hip_runtime.h>

#define NN 50000
#define NE 800000

// ---- bf16 helpers (manual RNE; values are finite) --------------------------
__device__ inline unsigned short f2bf(float f) {
    unsigned u = __float_as_uint(f);
    unsigned r = (u + 0x7FFFu + ((u >> 16) & 1u)) >> 16;
    return (unsigned short)r;
}
__device__ inline float bf2f(unsigned short h) {
    return __uint_as_float(((unsigned)h) << 16);
}

// ---- fused: degree/cursor atomics + proj0 (feat @ W0, UNscaled) ------------
// The graph build (atomics, memory-side-bound, CUs idle) and the K=256 GEMM
// (compute-bound, no graph dependency) overlap in one launch. Role by
// blockIdx: bid%5==0 -> proj tile bid/5 (782 tiles), else degree block
// (3125 blocks, 1 edge/thread). dout_is scaling moved to gather-0
// ((s*x)@W == s*(x@W)), so proj0 needs no degree data.
__global__ __launch_bounds__(256) void fused_build_proj0_kernel(
    const float* __restrict__ A,          // feat, lda=256
    const float* __restrict__ W,          // 256x64 row-major
    unsigned short* __restrict__ Xh,      // bf16 out, 50000x64
    const int* __restrict__ src, const int* __restrict__ dst,
    int* __restrict__ dout_cnt, int* __restrict__ cursor,
    int* __restrict__ epos) {
    __shared__ float sAT[64 * 68];  // [k][row], pitch 68
    __shared__ float sW[64 * 64];   // [k][col]

    const int bid = blockIdx.x;
    if (bid % 5 != 0) {
        // ---- degree / CSR-slot role: 1 edge per thread ----
        int d = bid - bid / 5 - 1;            // dense degree-block id 0..3124
        int e = d * 256 + threadIdx.x;        // < NE by construction
        int s = src[e], dn = dst[e];
        int pa = atomicAdd(&cursor[dn], 1);   // slot within dst row (din count)
        atomicAdd(&dout_cnt[s], 1);
        epos[e] = pa;
        return;
    }

    // ---- proj role: 64x64 tile of X = feat @ W0 (no scale) ----
    const int p = bid / 5;                    // tile id 0..781
    constexpr int lda = 256;
    constexpr int KC = 64;
    constexpr int NCHUNK = 4;                 // K = 256
    float acc[4][4] = {};

    const int t = threadIdx.x;
    const int tx = t & 15;
    const int ty = t >> 4;
    const int row0 = p * 64;

    const int srow = t & 63;
    const int f0 = t >> 6;
    int grow = row0 + srow;
    if (grow > NN - 1) grow = NN - 1;         // clamp: loads always in-bounds
    const float* arow = A + (size_t)grow * lda;

    for (int kc = 0; kc < NCHUNK; ++kc) {
#pragma unroll
        for (int it = 0; it < 4; ++it) {
            int k = (f0 + it * 4) * 4;
            float4 a4 = *reinterpret_cast<const float4*>(arow + kc * KC + k);
            sAT[(k + 0) * 68 + srow] = a4.x;
            sAT[(k + 1) * 68 + srow] = a4.y;
            sAT[(k + 2) * 68 + srow] = a4.z;
            sAT[(k + 3) * 68 + srow] = a4.w;
        }
        {
            const float4* wsrc = reinterpret_cast<const float4*>(W + (size_t)kc * KC * 64);
            float4* wdst = reinterpret_cast<float4*>(sW);
#pragma unroll
            for (int it = 0; it < 4; ++it) wdst[t + it * 256] = wsrc[t + it * 256];
        }
        __syncthreads();
#pragma unroll 8
        for (int k = 0; k < KC; ++k) {
            float4 av = *reinterpret_cast<const float4*>(&sAT[k * 68 + ty * 4]);
            float4 wv = *reinterpret_cast<const float4*>(&sW[k * 64 + tx * 4]);
            acc[0][0] = fmaf(av.x, wv.x, acc[0][0]);
            acc[0][1] = fmaf(av.x, wv.y, acc[0][1]);
            acc[0][2] = fmaf(av.x, wv.z, acc[0][2]);
            acc[0][3] = fmaf(av.x, wv.w, acc[0][3]);
            acc[1][0] = fmaf(av.y, wv.x, acc[1][0]);
            acc[1][1] = fmaf(av.y, wv.y, acc[1][1]);
            acc[1][2] = fmaf(av.y, wv.z, acc[1][2]);
            acc[1][3] = fmaf(av.y, wv.w, acc[1][3]);
            acc[2][0] = fmaf(av.z, wv.x, acc[2][0]);
            acc[2][1] = fmaf(av.z, wv.y, acc[2][1]);
            acc[2][2] = fmaf(av.z, wv.z, acc[2][2]);
            acc[2][3] = fmaf(av.z, wv.w, acc[2][3]);
            acc[3][0] = fmaf(av.w, wv.x, acc[3][0]);
            acc[3][1] = fmaf(av.w, wv.y, acc[3][1]);
            acc[3][2] = fmaf(av.w, wv.z, acc[3][2]);
            acc[3][3] = fmaf(av.w, wv.w, acc[3][3]);
        }
        __syncthreads();
    }
#pragma unroll
    for (int i = 0; i < 4; ++i) {
        int r = row0 + ty * 4 + i;
        if (r < NN) {
            ushort4 h = {f2bf(acc[i][0]), f2bf(acc[i][1]), f2bf(acc[i][2]), f2bf(acc[i][3])};
            *reinterpret_cast<ushort4*>(Xh + (size_t)r * 64 + tx * 4) = h;
        }
    }
}

// ---- scan helpers ----------------------------------------------------------
__device__ inline int wave_incl_scan(int v) {
    int lane = threadIdx.x & 63;
#pragma unroll
    for (int off = 1; off < 64; off <<= 1) {
        int t = __shfl_up(v, off, 64);
        if (lane >= off) v += t;
    }
    return v;
}

// A: per-block local exclusive scan of in-degree; block totals to partials
__global__ void scan_local_kernel(const int* __restrict__ din_cnt,
                                  int* __restrict__ row_start,
                                  int* __restrict__ partials) {
    __shared__ int wsum[4];
    int i = blockIdx.x * 256 + threadIdx.x;
    int v = (i < NN) ? din_cnt[i] : 0;
    int lane = threadIdx.x & 63, wid = threadIdx.x >> 6;
    int incl = wave_incl_scan(v);
    if (lane == 63) wsum[wid] = incl;
    __syncthreads();
    if (threadIdx.x == 0) {
        int s = 0;
        for (int w = 0; w < 4; ++w) { int t = wsum[w]; wsum[w] = s; s += t; }
        partials[blockIdx.x] = s;
    }
    __syncthreads();
    if (i < NN) row_start[i] = incl - v + wsum[wid];
}

// B: single-block exclusive scan of the 196 partials (in place)
__global__ void scan_partials_kernel(int* __restrict__ partials, int nparts,
                                     int* __restrict__ row_start) {
    __shared__ int wsum[4];
    int v = (threadIdx.x < nparts) ? partials[threadIdx.x] : 0;
    int lane = threadIdx.x & 63, wid = threadIdx.x >> 6;
    int incl = wave_incl_scan(v);
    if (lane == 63) wsum[wid] = incl;
    __syncthreads();
    if (threadIdx.x == 0) {
        int s = 0;
        for (int w = 0; w < 4; ++w) { int t = wsum[w]; wsum[w] = s; s += t; }
        row_start[NN] = NE;  // total in-degree == edge count
    }
    __syncthreads();
    if (threadIdx.x < nparts) partials[threadIdx.x] = incl - v + wsum[wid];
}

// C: add block offsets + emit rsqrt normalizers (fused, one pass over nodes)
__global__ void scan_add_norm_kernel(int* __restrict__ row_start, const int* __restrict__ partials,
                                     const int* __restrict__ dout_cnt, const int* __restrict__ din_cnt,
                                     float* __restrict__ dout_is, float* __restrict__ din_is) {
    int i = blockIdx.x * 256 + threadIdx.x;
    if (i < NN) {
        row_start[i] += partials[blockIdx.x];
        dout_is[i] = rsqrtf(fmaxf((float)dout_cnt[i], 1.0f));
        din_is[i]  = rsqrtf(fmaxf((float)din_cnt[i], 1.0f));
    }
}

// fill CSR: atomic-free scattered write using precomputed slots
__global__ void csr_fill_kernel(const int* __restrict__ src, const int* __restrict__ dst,
                                const int* __restrict__ row_start, const int* __restrict__ epos,
                                int* __restrict__ csr_src) {
    int e = blockIdx.x * 256 + threadIdx.x;
    if (e < NE) csr_src[row_start[dst[e]] + epos[e]] = src[e];
}

// ---- X = rowscale(A) @ W, register-blocked 64x64 tile (layers 1-3, tail) ---
template <int K, bool OUT_BF16>
__global__ __launch_bounds__(256) void proj_kernel(
    const float* __restrict__ A, int lda,
    const float* __restrict__ W,   // K x 64, row-major
    const float* __restrict__ scale,
    void* __restrict__ Xout) {
    constexpr int KC = 64;
    constexpr int NCHUNK = K / KC;
    __shared__ float sAT[KC * 68];  // [k][row], pitch 68
    __shared__ float sW[KC * 64];   // [k][col]
    float acc[4][4] = {};

    const int t = threadIdx.x;
    const int tx = t & 15;          // col group: cols 4*tx..4*tx+3
    const int ty = t >> 4;          // row group: rows 4*ty..4*ty+3
    const int row0 = blockIdx.x * 64;

    const int srow = t & 63;        // staging: one row per lane
    const int f0 = t >> 6;          // staging float4-col base (0..3)
    int grow = row0 + srow;
    if (grow > NN - 1) grow = NN - 1;   // clamp: loads always in-bounds
    const float* arow = A + (size_t)grow * lda;

    for (int kc = 0; kc < NCHUNK; ++kc) {
#pragma unroll
        for (int it = 0; it < 4; ++it) {
            int k = (f0 + it * 4) * 4;
            float4 a4 = *reinterpret_cast<const float4*>(arow + kc * KC + k);
            sAT[(k + 0) * 68 + srow] = a4.x;
            sAT[(k + 1) * 68 + srow] = a4.y;
            sAT[(k + 2) * 68 + srow] = a4.z;
            sAT[(k + 3) * 68 + srow] = a4.w;
        }
        {
            const float4* wsrc = reinterpret_cast<const float4*>(W + (size_t)kc * KC * 64);
            float4* wdst = reinterpret_cast<float4*>(sW);
#pragma unroll
            for (int it = 0; it < 4; ++it) wdst[t + it * 256] = wsrc[t + it * 256];
        }
        __syncthreads();
#pragma unroll 8
        for (int k = 0; k < KC; ++k) {
            float4 av = *reinterpret_cast<const float4*>(&sAT[k * 68 + ty * 4]);
            float4 wv = *reinterpret_cast<const float4*>(&sW[k * 64 + tx * 4]);
            acc[0][0] = fmaf(av.x, wv.x, acc[0][0]);
            acc[0][1] = fmaf(av.x, wv.y, acc[0][1]);
            acc[0][2] = fmaf(av.x, wv.z, acc[0][2]);
            acc[0][3] = fmaf(av.x, wv.w, acc[0][3]);
            acc[1][0] = fmaf(av.y, wv.x, acc[1][0]);
            acc[1][1] = fmaf(av.y, wv.y, acc[1][1]);
            acc[1][2] = fmaf(av.y, wv.z, acc[1][2]);
            acc[1][3] = fmaf(av.y, wv.w, acc[1][3]);
            acc[2][0] = fmaf(av.z, wv.x, acc[2][0]);
            acc[2][1] = fmaf(av.z, wv.y, acc[2][1]);
            acc[2][2] = fmaf(av.z, wv.z, acc[2][2]);
            acc[2][3] = fmaf(av.z, wv.w, acc[2][3]);
            acc[3][0] = fmaf(av.w, wv.x, acc[3][0]);
            acc[3][1] = fmaf(av.w, wv.y, acc[3][1]);
            acc[3][2] = fmaf(av.w, wv.z, acc[3][2]);
            acc[3][3] = fmaf(av.w, wv.w, acc[3][3]);
        }
        __syncthreads();
    }
#pragma unroll
    for (int i = 0; i < 4; ++i) {
        int r = row0 + ty * 4 + i;
        if (r < NN) {
            float s = scale ? scale[r] : 1.0f;
            float4 o = {acc[i][0] * s, acc[i][1] * s, acc[i][2] * s, acc[i][3] * s};
            if (OUT_BF16) {
                ushort4 h = {f2bf(o.x), f2bf(o.y), f2bf(o.z), f2bf(o.w)};
                *reinterpret_cast<ushort4*>((unsigned short*)Xout + (size_t)r * 64 + tx * 4) = h;
            } else {
                *reinterpret_cast<float4*>((float*)Xout + (size_t)r * 64 + tx * 4) = o;
            }
        }
    }
}

// ---- pull aggregation, up to 4 row-loads in flight per wave ----------------
// SSCALE: multiply each neighbor row by sscale[src] (layer 0: dout_is moved
// here from proj0 so proj0 could run before degrees exist). The sscale load is
// per-neighbor scalar and L2-resident (200KB table).
template <bool SSCALE>
__device__ inline void acc_row(double& a0, double& a1, double& a2, double& a3,
                               ushort4 v, float w) {
    if (SSCALE) {
        a0 += (double)(bf2f(v.x) * w); a1 += (double)(bf2f(v.y) * w);
        a2 += (double)(bf2f(v.z) * w); a3 += (double)(bf2f(v.w) * w);
    } else {
        a0 += (double)bf2f(v.x); a1 += (double)bf2f(v.y);
        a2 += (double)bf2f(v.z); a3 += (double)bf2f(v.w);
    }
}

template <bool SSCALE>
__global__ __launch_bounds__(256) void gather4_bf16_kernel(
    const int* __restrict__ row_start, const int* __restrict__ csr_src,
    const unsigned short* __restrict__ Xh, const float* __restrict__ din_is,
    const float* __restrict__ sscale,
    const float* __restrict__ b, float* __restrict__ out,
    int ldo, int coff, int relu) {
    int n = blockIdx.x * 4 + (threadIdx.x >> 6);
    if (n >= NN) return;
    int lane = threadIdx.x & 63;
    int g = lane >> 4;              // neighbor group 0..3
    int c4 = (lane & 15) << 2;      // cols c4..c4+3
    int s0 = row_start[n], s1 = row_start[n + 1];
    double a0 = 0.0, a1 = 0.0, a2 = 0.0, a3 = 0.0;
    int i = s0;
    // 16 neighbors/iter: 4 independent row loads in flight
    for (; i + 16 <= s1; i += 16) {
        int ia = csr_src[i + g];
        int ib = csr_src[i + 4 + g];
        int ic = csr_src[i + 8 + g];
        int id = csr_src[i + 12 + g];
        ushort4 va = *reinterpret_cast<const ushort4*>(Xh + (size_t)ia * 64 + c4);
        ushort4 vb = *reinterpret_cast<const ushort4*>(Xh + (size_t)ib * 64 + c4);
        ushort4 vc = *reinterpret_cast<const ushort4*>(Xh + (size_t)ic * 64 + c4);
        ushort4 vd = *reinterpret_cast<const ushort4*>(Xh + (size_t)id * 64 + c4);
        float wa = SSCALE ? sscale[ia] : 1.0f;
        float wb = SSCALE ? sscale[ib] : 1.0f;
        float wc = SSCALE ? sscale[ic] : 1.0f;
        float wd = SSCALE ? sscale[id] : 1.0f;
        acc_row<SSCALE>(a0, a1, a2, a3, va, wa);
        acc_row<SSCALE>(a0, a1, a2, a3, vb, wb);
        acc_row<SSCALE>(a0, a1, a2, a3, vc, wc);
        acc_row<SSCALE>(a0, a1, a2, a3, vd, wd);
    }
    // 8 neighbors/iter: 2 loads in flight
    for (; i + 8 <= s1; i += 8) {
        int ia = csr_src[i + g];
        int ib = csr_src[i + 4 + g];
        ushort4 va = *reinterpret_cast<const ushort4*>(Xh + (size_t)ia * 64 + c4);
        ushort4 vb = *reinterpret_cast<const ushort4*>(Xh + (size_t)ib * 64 + c4);
        float wa = SSCALE ? sscale[ia] : 1.0f;
        float wb = SSCALE ? sscale[ib] : 1.0f;
        acc_row<SSCALE>(a0, a1, a2, a3, va, wa);
        acc_row<SSCALE>(a0, a1, a2, a3, vb, wb);
    }
    // 4 neighbors
    for (; i + 4 <= s1; i += 4) {
        int ia = csr_src[i + g];
        ushort4 va = *reinterpret_cast<const ushort4*>(Xh + (size_t)ia * 64 + c4);
        float wa = SSCALE ? sscale[ia] : 1.0f;
        acc_row<SSCALE>(a0, a1, a2, a3, va, wa);
    }
    // <4 remaining, group-guarded
    if (i + g < s1) {
        int ia = csr_src[i + g];
        ushort4 va = *reinterpret_cast<const ushort4*>(Xh + (size_t)ia * 64 + c4);
        float wa = SSCALE ? sscale[ia] : 1.0f;
        acc_row<SSCALE>(a0, a1, a2, a3, va, wa);
    }
    // combine the 4 groups (lanes l, l^16, l^32, l^48 share the same c4)
    a0 += __shfl_xor(a0, 16, 64); a0 += __shfl_xor(a0, 32, 64);
    a1 += __shfl_xor(a1, 16, 64); a1 += __shfl_xor(a1, 32, 64);
    a2 += __shfl_xor(a2, 16, 64); a2 += __shfl_xor(a2, 32, 64);
    a3 += __shfl_xor(a3, 16, 64); a3 += __shfl_xor(a3, 32, 64);
    if (g == 0) {
        float4 o;
        if (relu) {
            float di = din_is[n];
            o.x = fmaxf(fmaf((float)a0, di, b[c4 + 0]), 0.0f);
            o.y = fmaxf(fmaf((float)a1, di, b[c4 + 1]), 0.0f);
            o.z = fmaxf(fmaf((float)a2, di, b[c4 + 2]), 0.0f);
            o.w = fmaxf(fmaf((float)a3, di, b[c4 + 3]), 0.0f);
        } else {
            o.x = (float)a0 + b[c4 + 0];
            o.y = (float)a1 + b[c4 + 1];
            o.z = (float)a2 + b[c4 + 2];
            o.w = (float)a3 + b[c4 + 3];
        }
        *reinterpret_cast<float4*>(out + (size_t)n * ldo + coff + c4) = o;
    }
}

extern "C" void kernel_launch(void* const* d_in, const int* in_sizes, int n_in,
                              void* d_out, int out_size, void* d_ws, size_t ws_size,
                              hipStream_t stream) {
    const float* feat  = (const float*)d_in[0];
    const int*   src   = (const int*)d_in[1];
    const int*   dst   = (const int*)d_in[2];
    const float* W[4]  = {(const float*)d_in[3], (const float*)d_in[5],
                          (const float*)d_in[7], (const float*)d_in[9]};
    const float* b[4]  = {(const float*)d_in[4], (const float*)d_in[6],
                          (const float*)d_in[8], (const float*)d_in[10]};
    const float* W_mlp = (const float*)d_in[11];
    const float* b_mlp = (const float*)d_in[12];
    float* out = (float*)d_out;

    // workspace layout:
    // C [NN*256 f]  (head transiently reused: dout_cnt [NN i] | cursor [NN i]
    //               | epos [NE i] — all dead before gather-0 writes C)
    // X [NN*64 f]   (bf16 view aliases the same region)
    // dout_is [NN f] | din_is [NN f] |
    // row_start [NN+1 i] | partials [256 i] | csr_src [NE i]
    float* C        = (float*)d_ws;
    int*   dout_cnt = (int*)d_ws;            // NN
    int*   cursor   = dout_cnt + NN;         // NN (doubles as din_cnt)
    int*   epos     = cursor + NN;           // NE
    float* X        = C + (size_t)NN * 256;
    unsigned short* Xh = (unsigned short*)X; // bf16 alias (used disjointly in time)
    float* dout_is  = X + (size_t)NN * 64;
    float* din_is   = dout_is + NN;
    int*   row_start = (int*)(din_is + NN);
    int*   partials  = row_start + NN + 1;
    int*   csr_src   = partials + 256;

    const int NBLK = (NN + 255) / 256;   // 196
    const int GBLK = (NN + 63) / 64;     // 782 (GEMM tiles)
    const int EBLK = (NE + 255) / 256;   // 3125
    const int DEGBLK = NE / 256;         // 3125 degree-role blocks (1 edge/thread)
    const int FBLK = GBLK + DEGBLK;      // 3907 fused blocks (782 proj @ bid%5==0)

    // zero dout_cnt + cursor (contiguous)
    hipMemsetAsync(dout_cnt, 0, 2 * NN * sizeof(int), stream);

    // fused: degree/cursor atomic pass overlapped with proj0 (unscaled feat@W0)
    fused_build_proj0_kernel<<<FBLK, 256, 0, stream>>>(feat, W[0], Xh,
                                                       src, dst, dout_cnt, cursor, epos);

    // row_start = exscan(cursor); fill is atomic-free
    scan_local_kernel<<<NBLK, 256, 0, stream>>>(cursor, row_start, partials);
    scan_partials_kernel<<<1, 256, 0, stream>>>(partials, NBLK, row_start);
    scan_add_norm_kernel<<<NBLK, 256, 0, stream>>>(row_start, partials, dout_cnt, cursor,
                                                   dout_is, din_is);
    csr_fill_kernel<<<EBLK, 256, 0, stream>>>(src, dst, row_start, epos, csr_src);

    // layer 0: X holds UNscaled feat@W0; dout_is applied per-src-row in gather
    gather4_bf16_kernel<true><<<12500, 256, 0, stream>>>(row_start, csr_src, Xh, din_is,
                                                         dout_is, b[0], C, 256, 0, 1);

    // layers 1..3 (K = 64), input = previous slice of C — bf16 X, pre-scaled
    for (int i = 1; i < 4; ++i) {
        proj_kernel<64, true><<<GBLK, 256, 0, stream>>>(C + (i - 1) * 64, 256, W[i], dout_is, Xh);
        gather4_bf16_kernel<false><<<12500, 256, 0, stream>>>(row_start, csr_src, Xh, din_is,
                                                              nullptr, b[i], C, 256, i * 64, 1);
    }

    // tail: P = C @ W_mlp as bf16 (project BEFORE the neighbor-sum; linear),
    // then out = b_mlp + segment_sum(P[src] -> dst)
    proj_kernel<256, true><<<GBLK, 256, 0, stream>>>(C, 256, W_mlp, nullptr, Xh);
    gather4_bf16_kernel<false><<<12500, 256, 0, stream>>>(row_start, csr_src, Xh, nullptr,
                                                          nullptr, b_mlp, out, 64, 0, 0);
}

// Round 3
// 394.168 us; speedup vs baseline: 1.0635x; 1.0106x over previous
//
#include <hip/hip_runtime.h>

#define NN 50000
#define NE 800000

// ---- bf16 helpers (manual RNE; values are finite) --------------------------
__device__ inline unsigned short f2bf(float f) {
    unsigned u = __float_as_uint(f);
    unsigned r = (u + 0x7FFFu + ((u >> 16) & 1u)) >> 16;
    return (unsigned short)r;
}
__device__ inline float bf2f(unsigned short h) {
    return __uint_as_float(((unsigned)h) << 16);
}

// ---- fused: degree/cursor atomics + proj0 (feat @ W0, UNscaled) ------------
// Degree role is atomic-return-latency bound: a wave with ONE cursor
// atomic in flight sustains ~20 G atomics/s chip-wide (89us). Unroll to
// 8 edges/thread: issue all 8 atomic-with-return before consuming any
// -> 8x outstanding returns per wave. dout atomics are fire-and-forget
// (no return consumed), issued after, never block. Role by blockIdx:
// bid%3==0 -> degree block (391 blocks, 2048 edges each), else proj tile
// (782). dout_is scaling lives in gather-0 ((s*x)@W == s*(x@W)), so proj0
// needs no degree data.
__global__ __launch_bounds__(256) void fused_build_proj0_kernel(
    const float* __restrict__ A,          // feat, lda=256
    const float* __restrict__ W,          // 256x64 row-major
    unsigned short* __restrict__ Xh,      // bf16 out, 50000x64
    const int* __restrict__ src, const int* __restrict__ dst,
    int* __restrict__ dout_cnt, int* __restrict__ cursor,
    int* __restrict__ epos) {
    __shared__ float sAT[64 * 68];  // [k][row], pitch 68
    __shared__ float sW[64 * 64];   // [k][col]

    const int bid = blockIdx.x;
    if (bid % 3 == 0) {
        // ---- degree / CSR-slot role: 8 edges per thread, atomics unrolled --
        const int d = bid / 3;                  // 0..390
        const int e0 = d * 2048 + threadIdx.x;  // stride-256 over 8 slots
        int s[8], dn[8], p[8];
#pragma unroll
        for (int j = 0; j < 8; ++j) {
            int e = e0 + j * 256;
            if (e < NE) { s[j] = src[e]; dn[j] = dst[e]; } else dn[j] = -1;
        }
        // 8 atomic-with-return in flight before any use of a result
#pragma unroll
        for (int j = 0; j < 8; ++j)
            if (dn[j] >= 0) p[j] = atomicAdd(&cursor[dn[j]], 1);
        // fire-and-forget out-degree histogram (no return consumed)
#pragma unroll
        for (int j = 0; j < 8; ++j)
            if (dn[j] >= 0) atomicAdd(&dout_cnt[s[j]], 1);
#pragma unroll
        for (int j = 0; j < 8; ++j) {
            int e = e0 + j * 256;
            if (e < NE) epos[e] = p[j];
        }
        return;
    }

    // ---- proj role: 64x64 tile of X = feat @ W0 (no scale) ----
    const int p = bid - bid / 3 - 1;          // tile id 0..781
    constexpr int lda = 256;
    constexpr int KC = 64;
    constexpr int NCHUNK = 4;                 // K = 256
    float acc[4][4] = {};

    const int t = threadIdx.x;
    const int tx = t & 15;
    const int ty = t >> 4;
    const int row0 = p * 64;

    const int srow = t & 63;
    const int f0 = t >> 6;
    int grow = row0 + srow;
    if (grow > NN - 1) grow = NN - 1;         // clamp: loads always in-bounds
    const float* arow = A + (size_t)grow * lda;

    for (int kc = 0; kc < NCHUNK; ++kc) {
#pragma unroll
        for (int it = 0; it < 4; ++it) {
            int k = (f0 + it * 4) * 4;
            float4 a4 = *reinterpret_cast<const float4*>(arow + kc * KC + k);
            sAT[(k + 0) * 68 + srow] = a4.x;
            sAT[(k + 1) * 68 + srow] = a4.y;
            sAT[(k + 2) * 68 + srow] = a4.z;
            sAT[(k + 3) * 68 + srow] = a4.w;
        }
        {
            const float4* wsrc = reinterpret_cast<const float4*>(W + (size_t)kc * KC * 64);
            float4* wdst = reinterpret_cast<float4*>(sW);
#pragma unroll
            for (int it = 0; it < 4; ++it) wdst[t + it * 256] = wsrc[t + it * 256];
        }
        __syncthreads();
#pragma unroll 8
        for (int k = 0; k < KC; ++k) {
            float4 av = *reinterpret_cast<const float4*>(&sAT[k * 68 + ty * 4]);
            float4 wv = *reinterpret_cast<const float4*>(&sW[k * 64 + tx * 4]);
            acc[0][0] = fmaf(av.x, wv.x, acc[0][0]);
            acc[0][1] = fmaf(av.x, wv.y, acc[0][1]);
            acc[0][2] = fmaf(av.x, wv.z, acc[0][2]);
            acc[0][3] = fmaf(av.x, wv.w, acc[0][3]);
            acc[1][0] = fmaf(av.y, wv.x, acc[1][0]);
            acc[1][1] = fmaf(av.y, wv.y, acc[1][1]);
            acc[1][2] = fmaf(av.y, wv.z, acc[1][2]);
            acc[1][3] = fmaf(av.y, wv.w, acc[1][3]);
            acc[2][0] = fmaf(av.z, wv.x, acc[2][0]);
            acc[2][1] = fmaf(av.z, wv.y, acc[2][1]);
            acc[2][2] = fmaf(av.z, wv.z, acc[2][2]);
            acc[2][3] = fmaf(av.z, wv.w, acc[2][3]);
            acc[3][0] = fmaf(av.w, wv.x, acc[3][0]);
            acc[3][1] = fmaf(av.w, wv.y, acc[3][1]);
            acc[3][2] = fmaf(av.w, wv.z, acc[3][2]);
            acc[3][3] = fmaf(av.w, wv.w, acc[3][3]);
        }
        __syncthreads();
    }
#pragma unroll
    for (int i = 0; i < 4; ++i) {
        int r = row0 + ty * 4 + i;
        if (r < NN) {
            ushort4 h = {f2bf(acc[i][0]), f2bf(acc[i][1]), f2bf(acc[i][2]), f2bf(acc[i][3])};
            *reinterpret_cast<ushort4*>(Xh + (size_t)r * 64 + tx * 4) = h;
        }
    }
}

// ---- scan helpers ----------------------------------------------------------
__device__ inline int wave_incl_scan(int v) {
    int lane = threadIdx.x & 63;
#pragma unroll
    for (int off = 1; off < 64; off <<= 1) {
        int t = __shfl_up(v, off, 64);
        if (lane >= off) v += t;
    }
    return v;
}

// A: per-block local exclusive scan of in-degree; block totals to partials
__global__ void scan_local_kernel(const int* __restrict__ din_cnt,
                                  int* __restrict__ row_start,
                                  int* __restrict__ partials) {
    __shared__ int wsum[4];
    int i = blockIdx.x * 256 + threadIdx.x;
    int v = (i < NN) ? din_cnt[i] : 0;
    int lane = threadIdx.x & 63, wid = threadIdx.x >> 6;
    int incl = wave_incl_scan(v);
    if (lane == 63) wsum[wid] = incl;
    __syncthreads();
    if (threadIdx.x == 0) {
        int s = 0;
        for (int w = 0; w < 4; ++w) { int t = wsum[w]; wsum[w] = s; s += t; }
        partials[blockIdx.x] = s;
    }
    __syncthreads();
    if (i < NN) row_start[i] = incl - v + wsum[wid];
}

// B: single-block exclusive scan of the 196 partials (in place)
__global__ void scan_partials_kernel(int* __restrict__ partials, int nparts,
                                     int* __restrict__ row_start) {
    __shared__ int wsum[4];
    int v = (threadIdx.x < nparts) ? partials[threadIdx.x] : 0;
    int lane = threadIdx.x & 63, wid = threadIdx.x >> 6;
    int incl = wave_incl_scan(v);
    if (lane == 63) wsum[wid] = incl;
    __syncthreads();
    if (threadIdx.x == 0) {
        int s = 0;
        for (int w = 0; w < 4; ++w) { int t = wsum[w]; wsum[w] = s; s += t; }
        row_start[NN] = NE;  // total in-degree == edge count
    }
    __syncthreads();
    if (threadIdx.x < nparts) partials[threadIdx.x] = incl - v + wsum[wid];
}

// C: add block offsets + emit rsqrt normalizers (fused, one pass over nodes)
__global__ void scan_add_norm_kernel(int* __restrict__ row_start, const int* __restrict__ partials,
                                     const int* __restrict__ dout_cnt, const int* __restrict__ din_cnt,
                                     float* __restrict__ dout_is, float* __restrict__ din_is) {
    int i = blockIdx.x * 256 + threadIdx.x;
    if (i < NN) {
        row_start[i] += partials[blockIdx.x];
        dout_is[i] = rsqrtf(fmaxf((float)dout_cnt[i], 1.0f));
        din_is[i]  = rsqrtf(fmaxf((float)din_cnt[i], 1.0f));
    }
}

// fill CSR: atomic-free scattered write using precomputed slots
__global__ void csr_fill_kernel(const int* __restrict__ src, const int* __restrict__ dst,
                                const int* __restrict__ row_start, const int* __restrict__ epos,
                                int* __restrict__ csr_src) {
    int e = blockIdx.x * 256 + threadIdx.x;
    if (e < NE) csr_src[row_start[dst[e]] + epos[e]] = src[e];
}

// ---- X = rowscale(A) @ W, register-blocked 64x64 tile (layers 1-3, tail) ---
template <int K, bool OUT_BF16>
__global__ __launch_bounds__(256) void proj_kernel(
    const float* __restrict__ A, int lda,
    const float* __restrict__ W,   // K x 64, row-major
    const float* __restrict__ scale,
    void* __restrict__ Xout) {
    constexpr int KC = 64;
    constexpr int NCHUNK = K / KC;
    __shared__ float sAT[KC * 68];  // [k][row], pitch 68
    __shared__ float sW[KC * 64];   // [k][col]
    float acc[4][4] = {};

    const int t = threadIdx.x;
    const int tx = t & 15;          // col group: cols 4*tx..4*tx+3
    const int ty = t >> 4;          // row group: rows 4*ty..4*ty+3
    const int row0 = blockIdx.x * 64;

    const int srow = t & 63;        // staging: one row per lane
    const int f0 = t >> 6;          // staging float4-col base (0..3)
    int grow = row0 + srow;
    if (grow > NN - 1) grow = NN - 1;   // clamp: loads always in-bounds
    const float* arow = A + (size_t)grow * lda;

    for (int kc = 0; kc < NCHUNK; ++kc) {
#pragma unroll
        for (int it = 0; it < 4; ++it) {
            int k = (f0 + it * 4) * 4;
            float4 a4 = *reinterpret_cast<const float4*>(arow + kc * KC + k);
            sAT[(k + 0) * 68 + srow] = a4.x;
            sAT[(k + 1) * 68 + srow] = a4.y;
            sAT[(k + 2) * 68 + srow] = a4.z;
            sAT[(k + 3) * 68 + srow] = a4.w;
        }
        {
            const float4* wsrc = reinterpret_cast<const float4*>(W + (size_t)kc * KC * 64);
            float4* wdst = reinterpret_cast<float4*>(sW);
#pragma unroll
            for (int it = 0; it < 4; ++it) wdst[t + it * 256] = wsrc[t + it * 256];
        }
        __syncthreads();
#pragma unroll 8
        for (int k = 0; k < KC; ++k) {
            float4 av = *reinterpret_cast<const float4*>(&sAT[k * 68 + ty * 4]);
            float4 wv = *reinterpret_cast<const float4*>(&sW[k * 64 + tx * 4]);
            acc[0][0] = fmaf(av.x, wv.x, acc[0][0]);
            acc[0][1] = fmaf(av.x, wv.y, acc[0][1]);
            acc[0][2] = fmaf(av.x, wv.z, acc[0][2]);
            acc[0][3] = fmaf(av.x, wv.w, acc[0][3]);
            acc[1][0] = fmaf(av.y, wv.x, acc[1][0]);
            acc[1][1] = fmaf(av.y, wv.y, acc[1][1]);
            acc[1][2] = fmaf(av.y, wv.z, acc[1][2]);
            acc[1][3] = fmaf(av.y, wv.w, acc[1][3]);
            acc[2][0] = fmaf(av.z, wv.x, acc[2][0]);
            acc[2][1] = fmaf(av.z, wv.y, acc[2][1]);
            acc[2][2] = fmaf(av.z, wv.z, acc[2][2]);
            acc[2][3] = fmaf(av.z, wv.w, acc[2][3]);
            acc[3][0] = fmaf(av.w, wv.x, acc[3][0]);
            acc[3][1] = fmaf(av.w, wv.y, acc[3][1]);
            acc[3][2] = fmaf(av.w, wv.z, acc[3][2]);
            acc[3][3] = fmaf(av.w, wv.w, acc[3][3]);
        }
        __syncthreads();
    }
#pragma unroll
    for (int i = 0; i < 4; ++i) {
        int r = row0 + ty * 4 + i;
        if (r < NN) {
            float s = scale ? scale[r] : 1.0f;
            float4 o = {acc[i][0] * s, acc[i][1] * s, acc[i][2] * s, acc[i][3] * s};
            if (OUT_BF16) {
                ushort4 h = {f2bf(o.x), f2bf(o.y), f2bf(o.z), f2bf(o.w)};
                *reinterpret_cast<ushort4*>((unsigned short*)Xout + (size_t)r * 64 + tx * 4) = h;
            } else {
                *reinterpret_cast<float4*>((float*)Xout + (size_t)r * 64 + tx * 4) = o;
            }
        }
    }
}

// ---- pull aggregation, up to 4 row-loads in flight per wave ----------------
// SSCALE: multiply each neighbor row by sscale[src] (layer 0: dout_is moved
// here from proj0 so proj0 could run before degrees exist). The sscale load is
// per-neighbor scalar and L2-resident (200KB table).
template <bool SSCALE>
__device__ inline void acc_row(double& a0, double& a1, double& a2, double& a3,
                               ushort4 v, float w) {
    if (SSCALE) {
        a0 += (double)(bf2f(v.x) * w); a1 += (double)(bf2f(v.y) * w);
        a2 += (double)(bf2f(v.z) * w); a3 += (double)(bf2f(v.w) * w);
    } else {
        a0 += (double)bf2f(v.x); a1 += (double)bf2f(v.y);
        a2 += (double)bf2f(v.z); a3 += (double)bf2f(v.w);
    }
}

template <bool SSCALE>
__global__ __launch_bounds__(256) void gather4_bf16_kernel(
    const int* __restrict__ row_start, const int* __restrict__ csr_src,
    const unsigned short* __restrict__ Xh, const float* __restrict__ din_is,
    const float* __restrict__ sscale,
    const float* __restrict__ b, float* __restrict__ out,
    int ldo, int coff, int relu) {
    int n = blockIdx.x * 4 + (threadIdx.x >> 6);
    if (n >= NN) return;
    int lane = threadIdx.x & 63;
    int g = lane >> 4;              // neighbor group 0..3
    int c4 = (lane & 15) << 2;      // cols c4..c4+3
    int s0 = row_start[n], s1 = row_start[n + 1];
    double a0 = 0.0, a1 = 0.0, a2 = 0.0, a3 = 0.0;
    int i = s0;
    // 16 neighbors/iter: 4 independent row loads in flight
    for (; i + 16 <= s1; i += 16) {
        int ia = csr_src[i + g];
        int ib = csr_src[i + 4 + g];
        int ic = csr_src[i + 8 + g];
        int id = csr_src[i + 12 + g];
        ushort4 va = *reinterpret_cast<const ushort4*>(Xh + (size_t)ia * 64 + c4);
        ushort4 vb = *reinterpret_cast<const ushort4*>(Xh + (size_t)ib * 64 + c4);
        ushort4 vc = *reinterpret_cast<const ushort4*>(Xh + (size_t)ic * 64 + c4);
        ushort4 vd = *reinterpret_cast<const ushort4*>(Xh + (size_t)id * 64 + c4);
        float wa = SSCALE ? sscale[ia] : 1.0f;
        float wb = SSCALE ? sscale[ib] : 1.0f;
        float wc = SSCALE ? sscale[ic] : 1.0f;
        float wd = SSCALE ? sscale[id] : 1.0f;
        acc_row<SSCALE>(a0, a1, a2, a3, va, wa);
        acc_row<SSCALE>(a0, a1, a2, a3, vb, wb);
        acc_row<SSCALE>(a0, a1, a2, a3, vc, wc);
        acc_row<SSCALE>(a0, a1, a2, a3, vd, wd);
    }
    // 8 neighbors/iter: 2 loads in flight
    for (; i + 8 <= s1; i += 8) {
        int ia = csr_src[i + g];
        int ib = csr_src[i + 4 + g];
        ushort4 va = *reinterpret_cast<const ushort4*>(Xh + (size_t)ia * 64 + c4);
        ushort4 vb = *reinterpret_cast<const ushort4*>(Xh + (size_t)ib * 64 + c4);
        float wa = SSCALE ? sscale[ia] : 1.0f;
        float wb = SSCALE ? sscale[ib] : 1.0f;
        acc_row<SSCALE>(a0, a1, a2, a3, va, wa);
        acc_row<SSCALE>(a0, a1, a2, a3, vb, wb);
    }
    // 4 neighbors
    for (; i + 4 <= s1; i += 4) {
        int ia = csr_src[i + g];
        ushort4 va = *reinterpret_cast<const ushort4*>(Xh + (size_t)ia * 64 + c4);
        float wa = SSCALE ? sscale[ia] : 1.0f;
        acc_row<SSCALE>(a0, a1, a2, a3, va, wa);
    }
    // <4 remaining, group-guarded
    if (i + g < s1) {
        int ia = csr_src[i + g];
        ushort4 va = *reinterpret_cast<const ushort4*>(Xh + (size_t)ia * 64 + c4);
        float wa = SSCALE ? sscale[ia] : 1.0f;
        acc_row<SSCALE>(a0, a1, a2, a3, va, wa);
    }
    // combine the 4 groups (lanes l, l^16, l^32, l^48 share the same c4)
    a0 += __shfl_xor(a0, 16, 64); a0 += __shfl_xor(a0, 32, 64);
    a1 += __shfl_xor(a1, 16, 64); a1 += __shfl_xor(a1, 32, 64);
    a2 += __shfl_xor(a2, 16, 64); a2 += __shfl_xor(a2, 32, 64);
    a3 += __shfl_xor(a3, 16, 64); a3 += __shfl_xor(a3, 32, 64);
    if (g == 0) {
        float4 o;
        if (relu) {
            float di = din_is[n];
            o.x = fmaxf(fmaf((float)a0, di, b[c4 + 0]), 0.0f);
            o.y = fmaxf(fmaf((float)a1, di, b[c4 + 1]), 0.0f);
            o.z = fmaxf(fmaf((float)a2, di, b[c4 + 2]), 0.0f);
            o.w = fmaxf(fmaf((float)a3, di, b[c4 + 3]), 0.0f);
        } else {
            o.x = (float)a0 + b[c4 + 0];
            o.y = (float)a1 + b[c4 + 1];
            o.z = (float)a2 + b[c4 + 2];
            o.w = (float)a3 + b[c4 + 3];
        }
        *reinterpret_cast<float4*>(out + (size_t)n * ldo + coff + c4) = o;
    }
}

extern "C" void kernel_launch(void* const* d_in, const int* in_sizes, int n_in,
                              void* d_out, int out_size, void* d_ws, size_t ws_size,
                              hipStream_t stream) {
    const float* feat  = (const float*)d_in[0];
    const int*   src   = (const int*)d_in[1];
    const int*   dst   = (const int*)d_in[2];
    const float* W[4]  = {(const float*)d_in[3], (const float*)d_in[5],
                          (const float*)d_in[7], (const float*)d_in[9]};
    const float* b[4]  = {(const float*)d_in[4], (const float*)d_in[6],
                          (const float*)d_in[8], (const float*)d_in[10]};
    const float* W_mlp = (const float*)d_in[11];
    const float* b_mlp = (const float*)d_in[12];
    float* out = (float*)d_out;

    // workspace layout:
    // C [NN*256 f]  (head transiently reused: dout_cnt [NN i] | cursor [NN i]
    //               | epos [NE i] — all dead before gather-0 writes C)
    // X [NN*64 f]   (bf16 view aliases the same region)
    // dout_is [NN f] | din_is [NN f] |
    // row_start [NN+1 i] | partials [256 i] | csr_src [NE i]
    float* C        = (float*)d_ws;
    int*   dout_cnt = (int*)d_ws;            // NN
    int*   cursor   = dout_cnt + NN;         // NN (doubles as din_cnt)
    int*   epos     = cursor + NN;           // NE
    float* X        = C + (size_t)NN * 256;
    unsigned short* Xh = (unsigned short*)X; // bf16 alias (used disjointly in time)
    float* dout_is  = X + (size_t)NN * 64;
    float* din_is   = dout_is + NN;
    int*   row_start = (int*)(din_is + NN);
    int*   partials  = row_start + NN + 1;
    int*   csr_src   = partials + 256;

    const int NBLK = (NN + 255) / 256;   // 196
    const int GBLK = (NN + 63) / 64;     // 782 (GEMM tiles)
    const int EBLK = (NE + 255) / 256;   // 3125
    const int DEGBLK = (NE + 2047) / 2048;  // 391 degree blocks (8 edges/thread)
    const int FBLK = GBLK + DEGBLK;      // 1173 fused blocks (391 degree @ bid%3==0)

    // zero dout_cnt + cursor (contiguous)
    hipMemsetAsync(dout_cnt, 0, 2 * NN * sizeof(int), stream);

    // fused: degree/cursor atomic pass (8-deep unrolled) overlapped with proj0
    fused_build_proj0_kernel<<<FBLK, 256, 0, stream>>>(feat, W[0], Xh,
                                                       src, dst, dout_cnt, cursor, epos);

    // row_start = exscan(cursor); fill is atomic-free
    scan_local_kernel<<<NBLK, 256, 0, stream>>>(cursor, row_start, partials);
    scan_partials_kernel<<<1, 256, 0, stream>>>(partials, NBLK, row_start);
    scan_add_norm_kernel<<<NBLK, 256, 0, stream>>>(row_start, partials, dout_cnt, cursor,
                                                   dout_is, din_is);
    csr_fill_kernel<<<EBLK, 256, 0, stream>>>(src, dst, row_start, epos, csr_src);

    // layer 0: X holds UNscaled feat@W0; dout_is applied per-src-row in gather
    gather4_bf16_kernel<true><<<12500, 256, 0, stream>>>(row_start, csr_src, Xh, din_is,
                                                         dout_is, b[0], C, 256, 0, 1);

    // layers 1..3 (K = 64), input = previous slice of C — bf16 X, pre-scaled
    for (int i = 1; i < 4; ++i) {
        proj_kernel<64, true><<<GBLK, 256, 0, stream>>>(C + (i - 1) * 64, 256, W[i], dout_is, Xh);
        gather4_bf16_kernel<false><<<12500, 256, 0, stream>>>(row_start, csr_src, Xh, din_is,
                                                              nullptr, b[i], C, 256, i * 64, 1);
    }

    // tail: P = C @ W_mlp as bf16 (project BEFORE the neighbor-sum; linear),
    // then out = b_mlp + segment_sum(P[src] -> dst)
    proj_kernel<256, true><<<GBLK, 256, 0, stream>>>(C, 256, W_mlp, nullptr, Xh);
    gather4_bf16_kernel<false><<<12500, 256, 0, stream>>>(row_start, csr_src, Xh, nullptr,
                                                          nullptr, b_mlp, out, 64, 0, 0);
}

// Round 4
// 381.540 us; speedup vs baseline: 1.0987x; 1.0331x over previous
//
#include <hip/hip_runtime.h>

#define NN 50000
#define NE 800000

// ---- bf16 helpers (manual RNE; values are finite) --------------------------
__device__ inline unsigned short f2bf(float f) {
    unsigned u = __float_as_uint(f);
    unsigned r = (u + 0x7FFFu + ((u >> 16) & 1u)) >> 16;
    return (unsigned short)r;
}
__device__ inline float bf2f(unsigned short h) {
    return __uint_as_float(((unsigned)h) << 16);
}

// ---- fused: degree/cursor atomics + proj0 (feat @ W0, UNscaled) ------------
// Degree role is memory-side atomic-THROUGHPUT bound (~23 G ops/s at the
// coherence point; 8x outstanding returns changed nothing, r3). 1.6M ops is
// the structural floor for {din slot-assign with return + dout histogram};
// proj0 rides along on otherwise-idle CUs. Role by blockIdx: bid%3==0 ->
// degree block (391 blocks, 2048 edges, 8/thread), else proj tile (782).
// dout_is scaling lives in gather-0 ((s*x)@W == s*(x@W)).
__global__ __launch_bounds__(256) void fused_build_proj0_kernel(
    const float* __restrict__ A,          // feat, lda=256
    const float* __restrict__ W,          // 256x64 row-major
    unsigned short* __restrict__ Xh,      // bf16 out, 50000x64
    const int* __restrict__ src, const int* __restrict__ dst,
    int* __restrict__ dout_cnt, int* __restrict__ cursor,
    int* __restrict__ epos) {
    __shared__ float sAT[64 * 68];  // [k][row], pitch 68
    __shared__ float sW[64 * 64];   // [k][col]

    const int bid = blockIdx.x;
    if (bid % 3 == 0) {
        // ---- degree / CSR-slot role: 8 edges per thread, atomics unrolled --
        const int d = bid / 3;                  // 0..390
        const int e0 = d * 2048 + threadIdx.x;  // stride-256 over 8 slots
        int s[8], dn[8], p[8];
#pragma unroll
        for (int j = 0; j < 8; ++j) {
            int e = e0 + j * 256;
            if (e < NE) { s[j] = src[e]; dn[j] = dst[e]; } else dn[j] = -1;
        }
        // 8 atomic-with-return in flight before any use of a result
#pragma unroll
        for (int j = 0; j < 8; ++j)
            if (dn[j] >= 0) p[j] = atomicAdd(&cursor[dn[j]], 1);
        // fire-and-forget out-degree histogram (no return consumed)
#pragma unroll
        for (int j = 0; j < 8; ++j)
            if (dn[j] >= 0) atomicAdd(&dout_cnt[s[j]], 1);
#pragma unroll
        for (int j = 0; j < 8; ++j) {
            int e = e0 + j * 256;
            if (e < NE) epos[e] = p[j];
        }
        return;
    }

    // ---- proj role: 64x64 tile of X = feat @ W0 (no scale) ----
    const int p = bid - bid / 3 - 1;          // tile id 0..781
    constexpr int lda = 256;
    constexpr int KC = 64;
    constexpr int NCHUNK = 4;                 // K = 256
    float acc[4][4] = {};

    const int t = threadIdx.x;
    const int tx = t & 15;
    const int ty = t >> 4;
    const int row0 = p * 64;

    const int srow = t & 63;
    const int f0 = t >> 6;
    int grow = row0 + srow;
    if (grow > NN - 1) grow = NN - 1;         // clamp: loads always in-bounds
    const float* arow = A + (size_t)grow * lda;

    for (int kc = 0; kc < NCHUNK; ++kc) {
#pragma unroll
        for (int it = 0; it < 4; ++it) {
            int k = (f0 + it * 4) * 4;
            float4 a4 = *reinterpret_cast<const float4*>(arow + kc * KC + k);
            sAT[(k + 0) * 68 + srow] = a4.x;
            sAT[(k + 1) * 68 + srow] = a4.y;
            sAT[(k + 2) * 68 + srow] = a4.z;
            sAT[(k + 3) * 68 + srow] = a4.w;
        }
        {
            const float4* wsrc = reinterpret_cast<const float4*>(W + (size_t)kc * KC * 64);
            float4* wdst = reinterpret_cast<float4*>(sW);
#pragma unroll
            for (int it = 0; it < 4; ++it) wdst[t + it * 256] = wsrc[t + it * 256];
        }
        __syncthreads();
#pragma unroll 8
        for (int k = 0; k < KC; ++k) {
            float4 av = *reinterpret_cast<const float4*>(&sAT[k * 68 + ty * 4]);
            float4 wv = *reinterpret_cast<const float4*>(&sW[k * 64 + tx * 4]);
            acc[0][0] = fmaf(av.x, wv.x, acc[0][0]);
            acc[0][1] = fmaf(av.x, wv.y, acc[0][1]);
            acc[0][2] = fmaf(av.x, wv.z, acc[0][2]);
            acc[0][3] = fmaf(av.x, wv.w, acc[0][3]);
            acc[1][0] = fmaf(av.y, wv.x, acc[1][0]);
            acc[1][1] = fmaf(av.y, wv.y, acc[1][1]);
            acc[1][2] = fmaf(av.y, wv.z, acc[1][2]);
            acc[1][3] = fmaf(av.y, wv.w, acc[1][3]);
            acc[2][0] = fmaf(av.z, wv.x, acc[2][0]);
            acc[2][1] = fmaf(av.z, wv.y, acc[2][1]);
            acc[2][2] = fmaf(av.z, wv.z, acc[2][2]);
            acc[2][3] = fmaf(av.z, wv.w, acc[2][3]);
            acc[3][0] = fmaf(av.w, wv.x, acc[3][0]);
            acc[3][1] = fmaf(av.w, wv.y, acc[3][1]);
            acc[3][2] = fmaf(av.w, wv.z, acc[3][2]);
            acc[3][3] = fmaf(av.w, wv.w, acc[3][3]);
        }
        __syncthreads();
    }
#pragma unroll
    for (int i = 0; i < 4; ++i) {
        int r = row0 + ty * 4 + i;
        if (r < NN) {
            ushort4 h = {f2bf(acc[i][0]), f2bf(acc[i][1]), f2bf(acc[i][2]), f2bf(acc[i][3])};
            *reinterpret_cast<ushort4*>(Xh + (size_t)r * 64 + tx * 4) = h;
        }
    }
}

// ---- scan helpers ----------------------------------------------------------
__device__ inline int wave_incl_scan(int v) {
    int lane = threadIdx.x & 63;
#pragma unroll
    for (int off = 1; off < 64; off <<= 1) {
        int t = __shfl_up(v, off, 64);
        if (lane >= off) v += t;
    }
    return v;
}

// A: per-block local exclusive scan of in-degree; block totals to partials
__global__ void scan_local_kernel(const int* __restrict__ din_cnt,
                                  int* __restrict__ row_start,
                                  int* __restrict__ partials) {
    __shared__ int wsum[4];
    int i = blockIdx.x * 256 + threadIdx.x;
    int v = (i < NN) ? din_cnt[i] : 0;
    int lane = threadIdx.x & 63, wid = threadIdx.x >> 6;
    int incl = wave_incl_scan(v);
    if (lane == 63) wsum[wid] = incl;
    __syncthreads();
    if (threadIdx.x == 0) {
        int s = 0;
        for (int w = 0; w < 4; ++w) { int t = wsum[w]; wsum[w] = s; s += t; }
        partials[blockIdx.x] = s;
    }
    __syncthreads();
    if (i < NN) row_start[i] = incl - v + wsum[wid];
}

// B: single-block exclusive scan of the 196 partials (in place)
__global__ void scan_partials_kernel(int* __restrict__ partials, int nparts,
                                     int* __restrict__ row_start) {
    __shared__ int wsum[4];
    int v = (threadIdx.x < nparts) ? partials[threadIdx.x] : 0;
    int lane = threadIdx.x & 63, wid = threadIdx.x >> 6;
    int incl = wave_incl_scan(v);
    if (lane == 63) wsum[wid] = incl;
    __syncthreads();
    if (threadIdx.x == 0) {
        int s = 0;
        for (int w = 0; w < 4; ++w) { int t = wsum[w]; wsum[w] = s; s += t; }
        row_start[NN] = NE;  // total in-degree == edge count
    }
    __syncthreads();
    if (threadIdx.x < nparts) partials[threadIdx.x] = incl - v + wsum[wid];
}

// C: add block offsets + emit rsqrt normalizers (fused, one pass over nodes)
__global__ void scan_add_norm_kernel(int* __restrict__ row_start, const int* __restrict__ partials,
                                     const int* __restrict__ dout_cnt, const int* __restrict__ din_cnt,
                                     float* __restrict__ dout_is, float* __restrict__ din_is) {
    int i = blockIdx.x * 256 + threadIdx.x;
    if (i < NN) {
        row_start[i] += partials[blockIdx.x];
        dout_is[i] = rsqrtf(fmaxf((float)dout_cnt[i], 1.0f));
        din_is[i]  = rsqrtf(fmaxf((float)din_cnt[i], 1.0f));
    }
}

// fill CSR: atomic-free scattered write using precomputed slots
__global__ void csr_fill_kernel(const int* __restrict__ src, const int* __restrict__ dst,
                                const int* __restrict__ row_start, const int* __restrict__ epos,
                                int* __restrict__ csr_src) {
    int e = blockIdx.x * 256 + threadIdx.x;
    if (e < NE) csr_src[row_start[dst[e]] + epos[e]] = src[e];
}

// ---- X = rowscale(A) @ W, register-blocked 64x64 tile (layers 1-3, tail) ---
template <int K, bool OUT_BF16>
__global__ __launch_bounds__(256) void proj_kernel(
    const float* __restrict__ A, int lda,
    const float* __restrict__ W,   // K x 64, row-major
    const float* __restrict__ scale,
    void* __restrict__ Xout) {
    constexpr int KC = 64;
    constexpr int NCHUNK = K / KC;
    __shared__ float sAT[KC * 68];  // [k][row], pitch 68
    __shared__ float sW[KC * 64];   // [k][col]
    float acc[4][4] = {};

    const int t = threadIdx.x;
    const int tx = t & 15;          // col group: cols 4*tx..4*tx+3
    const int ty = t >> 4;          // row group: rows 4*ty..4*ty+3
    const int row0 = blockIdx.x * 64;

    const int srow = t & 63;        // staging: one row per lane
    const int f0 = t >> 6;          // staging float4-col base (0..3)
    int grow = row0 + srow;
    if (grow > NN - 1) grow = NN - 1;   // clamp: loads always in-bounds
    const float* arow = A + (size_t)grow * lda;

    for (int kc = 0; kc < NCHUNK; ++kc) {
#pragma unroll
        for (int it = 0; it < 4; ++it) {
            int k = (f0 + it * 4) * 4;
            float4 a4 = *reinterpret_cast<const float4*>(arow + kc * KC + k);
            sAT[(k + 0) * 68 + srow] = a4.x;
            sAT[(k + 1) * 68 + srow] = a4.y;
            sAT[(k + 2) * 68 + srow] = a4.z;
            sAT[(k + 3) * 68 + srow] = a4.w;
        }
        {
            const float4* wsrc = reinterpret_cast<const float4*>(W + (size_t)kc * KC * 64);
            float4* wdst = reinterpret_cast<float4*>(sW);
#pragma unroll
            for (int it = 0; it < 4; ++it) wdst[t + it * 256] = wsrc[t + it * 256];
        }
        __syncthreads();
#pragma unroll 8
        for (int k = 0; k < KC; ++k) {
            float4 av = *reinterpret_cast<const float4*>(&sAT[k * 68 + ty * 4]);
            float4 wv = *reinterpret_cast<const float4*>(&sW[k * 64 + tx * 4]);
            acc[0][0] = fmaf(av.x, wv.x, acc[0][0]);
            acc[0][1] = fmaf(av.x, wv.y, acc[0][1]);
            acc[0][2] = fmaf(av.x, wv.z, acc[0][2]);
            acc[0][3] = fmaf(av.x, wv.w, acc[0][3]);
            acc[1][0] = fmaf(av.y, wv.x, acc[1][0]);
            acc[1][1] = fmaf(av.y, wv.y, acc[1][1]);
            acc[1][2] = fmaf(av.y, wv.z, acc[1][2]);
            acc[1][3] = fmaf(av.y, wv.w, acc[1][3]);
            acc[2][0] = fmaf(av.z, wv.x, acc[2][0]);
            acc[2][1] = fmaf(av.z, wv.y, acc[2][1]);
            acc[2][2] = fmaf(av.z, wv.z, acc[2][2]);
            acc[2][3] = fmaf(av.z, wv.w, acc[2][3]);
            acc[3][0] = fmaf(av.w, wv.x, acc[3][0]);
            acc[3][1] = fmaf(av.w, wv.y, acc[3][1]);
            acc[3][2] = fmaf(av.w, wv.z, acc[3][2]);
            acc[3][3] = fmaf(av.w, wv.w, acc[3][3]);
        }
        __syncthreads();
    }
#pragma unroll
    for (int i = 0; i < 4; ++i) {
        int r = row0 + ty * 4 + i;
        if (r < NN) {
            float s = scale ? scale[r] : 1.0f;
            float4 o = {acc[i][0] * s, acc[i][1] * s, acc[i][2] * s, acc[i][3] * s};
            if (OUT_BF16) {
                ushort4 h = {f2bf(o.x), f2bf(o.y), f2bf(o.z), f2bf(o.w)};
                *reinterpret_cast<ushort4*>((unsigned short*)Xout + (size_t)r * 64 + tx * 4) = h;
            } else {
                *reinterpret_cast<float4*>((float*)Xout + (size_t)r * 64 + tx * 4) = o;
            }
        }
    }
}

// ---- pull aggregation: 8 groups x 8 cols, uint4 loads, f32 accumulate ------
// One wave per dst row. lane = group g (lane>>3) x col-oct c8 ((lane&7)*8).
// Each uint4 load covers a full 128B bf16 row across 8 lanes (dwordx4 =
// coalescing sweet spot); 8 groups x 2-deep unroll = 16 rows (cache lines)
// in flight per wave — same as the old 4x ushort4 shape with HALF the VMEM
// instructions. bf16 pairs unpack via shift/and; f32 accumulate (deg~16 sums
// of O(1) values: f32 error ~1e-6, far below the 0.4% bf16 quantization).
// SSCALE: multiply each neighbor row by sscale[src] (layer 0: dout_is moved
// here from proj0; L2-resident 200KB table).
// relu!=0: out = relu(sum*din_is[n] + b[c]);  relu==0: out = sum + b[c].
template <bool SSCALE>
__device__ inline void acc8(float* a, uint4 v, float w) {
    unsigned d0 = v.x, d1 = v.y, d2 = v.z, d3 = v.w;
    if (SSCALE) {
        a[0] = fmaf(__uint_as_float(d0 << 16), w, a[0]);
        a[1] = fmaf(__uint_as_float(d0 & 0xFFFF0000u), w, a[1]);
        a[2] = fmaf(__uint_as_float(d1 << 16), w, a[2]);
        a[3] = fmaf(__uint_as_float(d1 & 0xFFFF0000u), w, a[3]);
        a[4] = fmaf(__uint_as_float(d2 << 16), w, a[4]);
        a[5] = fmaf(__uint_as_float(d2 & 0xFFFF0000u), w, a[5]);
        a[6] = fmaf(__uint_as_float(d3 << 16), w, a[6]);
        a[7] = fmaf(__uint_as_float(d3 & 0xFFFF0000u), w, a[7]);
    } else {
        a[0] += __uint_as_float(d0 << 16);
        a[1] += __uint_as_float(d0 & 0xFFFF0000u);
        a[2] += __uint_as_float(d1 << 16);
        a[3] += __uint_as_float(d1 & 0xFFFF0000u);
        a[4] += __uint_as_float(d2 << 16);
        a[5] += __uint_as_float(d2 & 0xFFFF0000u);
        a[6] += __uint_as_float(d3 << 16);
        a[7] += __uint_as_float(d3 & 0xFFFF0000u);
    }
}

template <bool SSCALE>
__global__ __launch_bounds__(256) void gather8_bf16_kernel(
    const int* __restrict__ row_start, const int* __restrict__ csr_src,
    const unsigned short* __restrict__ Xh, const float* __restrict__ din_is,
    const float* __restrict__ sscale,
    const float* __restrict__ b, float* __restrict__ out,
    int ldo, int coff, int relu) {
    int n = blockIdx.x * 4 + (threadIdx.x >> 6);
    if (n >= NN) return;
    int lane = threadIdx.x & 63;
    int g = lane >> 3;              // neighbor group 0..7
    int c8 = (lane & 7) << 3;       // cols c8..c8+7
    int s0 = row_start[n], s1 = row_start[n + 1];
    float a[8] = {};
    int i = s0;
    // 16 neighbors/iter: 2 independent 16B row loads in flight per lane
    for (; i + 16 <= s1; i += 16) {
        int ia = csr_src[i + g];
        int ib = csr_src[i + 8 + g];
        uint4 va = *reinterpret_cast<const uint4*>(Xh + (size_t)ia * 64 + c8);
        uint4 vb = *reinterpret_cast<const uint4*>(Xh + (size_t)ib * 64 + c8);
        float wa = SSCALE ? sscale[ia] : 1.0f;
        float wb = SSCALE ? sscale[ib] : 1.0f;
        acc8<SSCALE>(a, va, wa);
        acc8<SSCALE>(a, vb, wb);
    }
    // 8 neighbors/iter
    for (; i + 8 <= s1; i += 8) {
        int ia = csr_src[i + g];
        uint4 va = *reinterpret_cast<const uint4*>(Xh + (size_t)ia * 64 + c8);
        float wa = SSCALE ? sscale[ia] : 1.0f;
        acc8<SSCALE>(a, va, wa);
    }
    // <8 remaining, group-guarded
    if (i + g < s1) {
        int ia = csr_src[i + g];
        uint4 va = *reinterpret_cast<const uint4*>(Xh + (size_t)ia * 64 + c8);
        float wa = SSCALE ? sscale[ia] : 1.0f;
        acc8<SSCALE>(a, va, wa);
    }
    // combine the 8 groups (lanes l, l^8, l^16, ..., l^56 share the same c8)
#pragma unroll
    for (int off = 8; off < 64; off <<= 1) {
#pragma unroll
        for (int j = 0; j < 8; ++j) a[j] += __shfl_xor(a[j], off, 64);
    }
    if (g == 0) {
        float4 o0, o1;
        if (relu) {
            float di = din_is[n];
            o0.x = fmaxf(fmaf(a[0], di, b[c8 + 0]), 0.0f);
            o0.y = fmaxf(fmaf(a[1], di, b[c8 + 1]), 0.0f);
            o0.z = fmaxf(fmaf(a[2], di, b[c8 + 2]), 0.0f);
            o0.w = fmaxf(fmaf(a[3], di, b[c8 + 3]), 0.0f);
            o1.x = fmaxf(fmaf(a[4], di, b[c8 + 4]), 0.0f);
            o1.y = fmaxf(fmaf(a[5], di, b[c8 + 5]), 0.0f);
            o1.z = fmaxf(fmaf(a[6], di, b[c8 + 6]), 0.0f);
            o1.w = fmaxf(fmaf(a[7], di, b[c8 + 7]), 0.0f);
        } else {
            o0.x = a[0] + b[c8 + 0];
            o0.y = a[1] + b[c8 + 1];
            o0.z = a[2] + b[c8 + 2];
            o0.w = a[3] + b[c8 + 3];
            o1.x = a[4] + b[c8 + 4];
            o1.y = a[5] + b[c8 + 5];
            o1.z = a[6] + b[c8 + 6];
            o1.w = a[7] + b[c8 + 7];
        }
        float* op = out + (size_t)n * ldo + coff + c8;
        *reinterpret_cast<float4*>(op) = o0;
        *reinterpret_cast<float4*>(op + 4) = o1;
    }
}

extern "C" void kernel_launch(void* const* d_in, const int* in_sizes, int n_in,
                              void* d_out, int out_size, void* d_ws, size_t ws_size,
                              hipStream_t stream) {
    const float* feat  = (const float*)d_in[0];
    const int*   src   = (const int*)d_in[1];
    const int*   dst   = (const int*)d_in[2];
    const float* W[4]  = {(const float*)d_in[3], (const float*)d_in[5],
                          (const float*)d_in[7], (const float*)d_in[9]};
    const float* b[4]  = {(const float*)d_in[4], (const float*)d_in[6],
                          (const float*)d_in[8], (const float*)d_in[10]};
    const float* W_mlp = (const float*)d_in[11];
    const float* b_mlp = (const float*)d_in[12];
    float* out = (float*)d_out;

    // workspace layout:
    // C [NN*256 f]  (head transiently reused: dout_cnt [NN i] | cursor [NN i]
    //               | epos [NE i] — all dead before gather-0 writes C)
    // X [NN*64 f]   (bf16 view aliases the same region)
    // dout_is [NN f] | din_is [NN f] |
    // row_start [NN+1 i] | partials [256 i] | csr_src [NE i]
    float* C        = (float*)d_ws;
    int*   dout_cnt = (int*)d_ws;            // NN
    int*   cursor   = dout_cnt + NN;         // NN (doubles as din_cnt)
    int*   epos     = cursor + NN;           // NE
    float* X        = C + (size_t)NN * 256;
    unsigned short* Xh = (unsigned short*)X; // bf16 alias (used disjointly in time)
    float* dout_is  = X + (size_t)NN * 64;
    float* din_is   = dout_is + NN;
    int*   row_start = (int*)(din_is + NN);
    int*   partials  = row_start + NN + 1;
    int*   csr_src   = partials + 256;

    const int NBLK = (NN + 255) / 256;   // 196
    const int GBLK = (NN + 63) / 64;     // 782 (GEMM tiles)
    const int EBLK = (NE + 255) / 256;   // 3125
    const int DEGBLK = (NE + 2047) / 2048;  // 391 degree blocks (8 edges/thread)
    const int FBLK = GBLK + DEGBLK;      // 1173 fused blocks (391 degree @ bid%3==0)

    // zero dout_cnt + cursor (contiguous)
    hipMemsetAsync(dout_cnt, 0, 2 * NN * sizeof(int), stream);

    // fused: degree/cursor atomic pass (8-deep unrolled) overlapped with proj0
    fused_build_proj0_kernel<<<FBLK, 256, 0, stream>>>(feat, W[0], Xh,
                                                       src, dst, dout_cnt, cursor, epos);

    // row_start = exscan(cursor); fill is atomic-free
    scan_local_kernel<<<NBLK, 256, 0, stream>>>(cursor, row_start, partials);
    scan_partials_kernel<<<1, 256, 0, stream>>>(partials, NBLK, row_start);
    scan_add_norm_kernel<<<NBLK, 256, 0, stream>>>(row_start, partials, dout_cnt, cursor,
                                                   dout_is, din_is);
    csr_fill_kernel<<<EBLK, 256, 0, stream>>>(src, dst, row_start, epos, csr_src);

    // layer 0: X holds UNscaled feat@W0; dout_is applied per-src-row in gather
    gather8_bf16_kernel<true><<<12500, 256, 0, stream>>>(row_start, csr_src, Xh, din_is,
                                                         dout_is, b[0], C, 256, 0, 1);

    // layers 1..3 (K = 64), input = previous slice of C — bf16 X, pre-scaled
    for (int i = 1; i < 4; ++i) {
        proj_kernel<64, true><<<GBLK, 256, 0, stream>>>(C + (i - 1) * 64, 256, W[i], dout_is, Xh);
        gather8_bf16_kernel<false><<<12500, 256, 0, stream>>>(row_start, csr_src, Xh, din_is,
                                                              nullptr, b[i], C, 256, i * 64, 1);
    }

    // tail: P = C @ W_mlp as bf16 (project BEFORE the neighbor-sum; linear),
    // then out = b_mlp + segment_sum(P[src] -> dst)
    proj_kernel<256, true><<<GBLK, 256, 0, stream>>>(C, 256, W_mlp, nullptr, Xh);
    gather8_bf16_kernel<false><<<12500, 256, 0, stream>>>(row_start, csr_src, Xh, nullptr,
                                                          nullptr, b_mlp, out, 64, 0, 0);
}